// Round 12
// baseline (220.343 us; speedup 1.0000x reference)
//
#include <hip/hip_runtime.h>
#include <math.h>

#define L_SEQ 384
#define E_DIM 512
#define NHEAD 8
#define NBH   16
#define HD    64
#define JSPLIT 12
#define JTILE  32          // L_SEQ / JSPLIT
#define PROJ_ELEMS (NBH * L_SEQ * HD)   // 393216
#define LOG2E 1.44269504f

typedef __attribute__((ext_vector_type(8))) __bf16 bf16x8;
typedef __attribute__((ext_vector_type(4))) float f32x4;
typedef __attribute__((ext_vector_type(2))) float f32x2;

__device__ __forceinline__ float uniform_f(float v) {
  return __uint_as_float(__builtin_amdgcn_readfirstlane(__float_as_uint(v)));
}

__device__ __forceinline__ unsigned f2bf(float f) {   // RNE float->bf16 bits
  unsigned u = __float_as_uint(f);
  return (u + 0x7FFFu + ((u >> 16) & 1u)) >> 16;
}

__device__ __forceinline__ bf16x8 cvt8(float4 a, float4 b) {  // 8 fp32 -> bf16x8
  union { bf16x8 v; unsigned u[4]; } r;
  r.u[0] = f2bf(a.x) | (f2bf(a.y) << 16);
  r.u[1] = f2bf(a.z) | (f2bf(a.w) << 16);
  r.u[2] = f2bf(b.x) | (f2bf(b.y) << 16);
  r.u[3] = f2bf(b.z) | (f2bf(b.w) << 16);
  return r.v;
}

// quad_perm DPP helpers (pure VALU, no LDS pipe)
__device__ __forceinline__ float quad_sum(float x) {
  x += __int_as_float(__builtin_amdgcn_mov_dpp(__float_as_int(x), 0xB1, 0xF, 0xF, 0)); // xor 1
  x += __int_as_float(__builtin_amdgcn_mov_dpp(__float_as_int(x), 0x4E, 0xF, 0xF, 0)); // xor 2
  return x;
}
template <int PAT>
__device__ __forceinline__ float quad_bcast(float x) {
  return __int_as_float(__builtin_amdgcn_mov_dpp(__float_as_int(x), PAT, 0xF, 0xF, 0));
}

// ---------------------------------------------------------------------------
// Convert x|Wq|Wk|Wv (contiguous dst1) and Wo (dst2) to bf16 (R5-proven).
// ---------------------------------------------------------------------------
__global__ __launch_bounds__(256) void to_bf16_all(
    const float* __restrict__ x, const float* __restrict__ Wq,
    const float* __restrict__ Wk, const float* __restrict__ Wv,
    const float* __restrict__ Wo, unsigned short* __restrict__ dst1,
    unsigned short* __restrict__ dst2)
{
  int e0 = (blockIdx.x * 256 + threadIdx.x) * 4;
  if (e0 >= 1441792) return;
  const float* src; unsigned short* d; int s;
  if (e0 < 393216)       { src = x;  s = e0;           d = dst1 + e0; }
  else if (e0 < 655360)  { src = Wq; s = e0 - 393216;  d = dst1 + e0; }
  else if (e0 < 917504)  { src = Wk; s = e0 - 655360;  d = dst1 + e0; }
  else if (e0 < 1179648) { src = Wv; s = e0 - 917504;  d = dst1 + e0; }
  else                   { src = Wo; s = e0 - 1179648; d = dst2 + s;  }
  float4 v = *(const float4*)(src + s);
  unsigned lo = f2bf(v.x) | (f2bf(v.y) << 16);
  unsigned hi = f2bf(v.z) | (f2bf(v.w) << 16);
  *(uint2*)d = make_uint2(lo, hi);
}

// ---------------------------------------------------------------------------
// Pure-bf16 MFMA GEMM (R5-proven) — Q/K/V projections only now.
// C = A @ B^T. Block 256 = 4 waves; tile 64x64; head-scatter epilogue.
// ---------------------------------------------------------------------------
__global__ __launch_bounds__(256) void gemm_mfma(
    const __bf16* __restrict__ A, const __bf16* __restrict__ B0,
    const __bf16* __restrict__ B1, const __bf16* __restrict__ B2,
    float* __restrict__ C0, float* __restrict__ C1, float* __restrict__ C2,
    int M, int N, int K)
{
  const int z = blockIdx.z;
  const __bf16* Bm = (z == 0) ? B0 : (z == 1) ? B1 : B2;
  float* Cp = (z == 0) ? C0 : (z == 1) ? C1 : C2;

  const int tid = threadIdx.x;
  const int wave = tid >> 6, lane = tid & 63;
  const int m0 = blockIdx.y * 64 + wave * 16;
  const int n0 = blockIdx.x * 64;
  const int mr = lane & 15, quad = lane >> 4;

  f32x4 acc[4];
  #pragma unroll
  for (int nt = 0; nt < 4; ++nt) acc[nt] = (f32x4){0.f, 0.f, 0.f, 0.f};

  const __bf16* ap = A + (size_t)(m0 + mr) * K + quad * 8;
  const __bf16* bp = Bm + (size_t)(n0 + mr) * K + quad * 8;

  #pragma unroll 4
  for (int k0 = 0; k0 < K; k0 += 32) {
    bf16x8 a = *(const bf16x8*)(ap + k0);
    #pragma unroll
    for (int nt = 0; nt < 4; ++nt) {
      bf16x8 b = *(const bf16x8*)(bp + (size_t)nt * 16 * K + k0);
      acc[nt] = __builtin_amdgcn_mfma_f32_16x16x32_bf16(a, b, acc[nt], 0, 0, 0);
    }
  }

  #pragma unroll
  for (int nt = 0; nt < 4; ++nt) {
    int n = n0 + nt * 16 + mr;
    #pragma unroll
    for (int r = 0; r < 4; ++r) {
      int m = m0 + quad * 4 + r;
      int b = m / L_SEQ, l = m % L_SEQ;
      int h = n >> 6, d = n & 63;
      Cp[((size_t)(b * NHEAD + h) * L_SEQ + l) * HD + d] = acc[nt][r];
    }
  }
}

// ---------------------------------------------------------------------------
// Fused pairwise core v9 = R11 math + bf16 K/V in LDS.
// LDS 16.4 -> 8.2 KB: occupancy was pinned at ~4.3 blocks/CU ~ 70KB/16.4KB
// (R3/R4/R5/R10); halving LDS should ~double resident blocks. Unpack cost:
// 4 bitops/atom (+~9% instr) on a 65%-VALUBusy kernel — net win if
// VALUBusy rises past ~75%.
// Block 128 = 32 i x 4 lanes, 4 atoms/thread; grid (12, 12, 16).
// ---------------------------------------------------------------------------
__global__ __launch_bounds__(128, 4) void berry_main(
    const float* __restrict__ Q, const float* __restrict__ K,
    const float* __restrict__ V, const float* __restrict__ dde_w,
    const float* __restrict__ dde_b, float* __restrict__ CTXS)
{
  __shared__ unsigned short ktb[JTILE][HD];   // normalized k atoms, bf16
  __shared__ unsigned short vtb[JTILE][HD];   // raw v, bf16

  const int tid = threadIdx.x;
  const int bh = blockIdx.z;
  const int i = blockIdx.y * 32 + (tid >> 2);
  const int ag = tid & 3;                 // lane-in-quad: atoms ag*4 .. ag*4+3
  const int js = blockIdx.x;
  const int j0 = js * JTILE;

  // this lane's gate row p = ag: weights * (-LOG2E/16), bias * (-LOG2E)
  float w0, w1, w2, w3, gbp;
  {
    float s[16];
    #pragma unroll
    for (int t = 0; t < 16; ++t) s[t] = uniform_f(dde_w[t]) * (-LOG2E * 0.0625f);
    float b0 = uniform_f(dde_b[0]) * -LOG2E, b1 = uniform_f(dde_b[1]) * -LOG2E;
    float b2 = uniform_f(dde_b[2]) * -LOG2E, b3 = uniform_f(dde_b[3]) * -LOG2E;
    w0  = (ag == 0) ? s[0]  : (ag == 1) ? s[4]  : (ag == 2) ? s[8]  : s[12];
    w1  = (ag == 0) ? s[1]  : (ag == 1) ? s[5]  : (ag == 2) ? s[9]  : s[13];
    w2  = (ag == 0) ? s[2]  : (ag == 1) ? s[6]  : (ag == 2) ? s[10] : s[14];
    w3  = (ag == 0) ? s[3]  : (ag == 1) ? s[7]  : (ag == 2) ? s[11] : s[15];
    gbp = (ag == 0) ? b0    : (ag == 1) ? b1    : (ag == 2) ? b2    : b3;
  }

  float4 qa[4];
  f32x2 c01[4], c23[4];
  const float* qp = Q + ((size_t)(bh * L_SEQ + i) * HD + ag * 16);
  #pragma unroll
  for (int t = 0; t < 4; ++t) {
    float4 q = ((const float4*)qp)[t];
    float d = q.x * q.x + q.y * q.y + q.z * q.z + q.w * q.w;
    float r = __builtin_amdgcn_rsqf(fmaxf(d, 1e-30f));
    qa[t].x = q.x * r; qa[t].y = q.y * r; qa[t].z = q.z * r; qa[t].w = q.w * r;
    c01[t] = (f32x2){0.f, 0.f};
    c23[t] = (f32x2){0.f, 0.f};
  }

  // stage K (normalized per atom: |ham(q,k)| = |q||k|) + V, packed bf16
  #pragma unroll
  for (int p = 0; p < 4; ++p) {
    int idx = tid + p * 128;
    int jj = idx >> 4, at = idx & 15;
    size_t g = (size_t)(bh * L_SEQ + j0 + jj) * HD + at * 4;
    float4 kq = *(const float4*)(K + g);
    float d = kq.x * kq.x + kq.y * kq.y + kq.z * kq.z + kq.w * kq.w;
    float r = __builtin_amdgcn_rsqf(fmaxf(d, 1e-30f));
    kq.x *= r; kq.y *= r; kq.z *= r; kq.w *= r;
    *(uint2*)&ktb[jj][at * 4] =
        make_uint2(f2bf(kq.x) | (f2bf(kq.y) << 16), f2bf(kq.z) | (f2bf(kq.w) << 16));
    float4 vq = *(const float4*)(V + g);
    *(uint2*)&vtb[jj][at * 4] =
        make_uint2(f2bf(vq.x) | (f2bf(vq.y) << 16), f2bf(vq.z) | (f2bf(vq.w) << 16));
  }
  __syncthreads();

  for (int jj = 0; jj < JTILE; ++jj) {
    f32x2 h01[4], h23[4];
    f32x2 gs01 = (f32x2){0.f, 0.f}, gs23 = (f32x2){0.f, 0.f};

    #pragma unroll
    for (int a = 0; a < 4; ++a) {
      uint2 ku = *(const uint2*)&ktb[jj][ag * 16 + a * 4];
      float kx = __uint_as_float(ku.x << 16);
      float ky = __uint_as_float(ku.x & 0xffff0000u);
      float kz = __uint_as_float(ku.y << 16);
      float kw = __uint_as_float(ku.y & 0xffff0000u);
      f32x2 k01 = (f32x2){kx, ky}, k23 = (f32x2){kz, kw};
      f32x2 s01 = (f32x2){ky, kx}, s23 = (f32x2){kw, kz};
      f32x2 qx2 = (f32x2){qa[a].x, qa[a].x};
      f32x2 qy2 = (f32x2){qa[a].y, qa[a].y};
      f32x2 qz2 = (f32x2){qa[a].z, qa[a].z};
      f32x2 qw2 = (f32x2){qa[a].w, qa[a].w};
      // h01 = qx*(kx,ky) + qy*(-ky,kx) + qz*(-kz,kw) + qw*(-kw,-kz)
      f32x2 t = qx2 * k01;
      t += qy2 * (f32x2){-s01.x, s01.y};
      t += qz2 * (f32x2){-k23.x, k23.y};
      t += qw2 * (f32x2){-s23.x, -s23.y};
      h01[a] = t;
      // h23 = qx*(kz,kw) + qy*(-kw,kz) + qz*(kx,-ky) + qw*(ky,kx)
      f32x2 u = qx2 * k23;
      u += qy2 * (f32x2){-s23.x, s23.y};
      u += qz2 * (f32x2){k01.x, -k01.y};
      u += qw2 * s01;
      h23[a] = u;
      gs01 += t; gs23 += u;
    }

    // 16-atom component sums across the quad (4 scalar DPP butterflies)
    float g0 = quad_sum(gs01.x), g1 = quad_sum(gs01.y);
    float g2 = quad_sum(gs23.x), g3 = quad_sum(gs23.y);

    // this lane's gate only (weights pre-scaled by -LOG2E/16), then share
    float tl = gbp + w0 * g0 + w1 * g1 + w2 * g2 + w3 * g3;
    float gown = __builtin_amdgcn_rcpf(1.f + __builtin_amdgcn_exp2f(tl));
    float gx = quad_bcast<0x00>(gown);
    float gy = quad_bcast<0x55>(gown);
    float gz = quad_bcast<0xAA>(gown);
    float gw_ = quad_bcast<0xFF>(gown);
    f32x2 gA = (f32x2){gx, gy}, gB = (f32x2){gz, gw_};

    #pragma unroll
    for (int a = 0; a < 4; ++a) {
      f32x2 sA = h01[a] * gA;            // (sx, sy)
      f32x2 sB = h23[a] * gB;            // (sz, sw)
      uint2 vu = *(const uint2*)&vtb[jj][ag * 16 + a * 4];
      float vx = __uint_as_float(vu.x << 16);
      float vy = __uint_as_float(vu.x & 0xffff0000u);
      float vz = __uint_as_float(vu.y << 16);
      float vw = __uint_as_float(vu.y & 0xffff0000u);
      f32x2 v01 = (f32x2){vx, vy}, v23 = (f32x2){vz, vw};
      f32x2 sv01 = (f32x2){vy, vx}, sv23 = (f32x2){vw, vz};
      f32x2 sx2 = (f32x2){sA.x, sA.x}, sy2 = (f32x2){sA.y, sA.y};
      f32x2 sz2 = (f32x2){sB.x, sB.x}, sw2 = (f32x2){sB.y, sB.y};
      // o01 += sx*(vx,vy) + sy*(-vy,vx) + sz*(-vz,vw) + sw*(-vw,-vz)
      c01[a] += sx2 * v01;
      c01[a] += sy2 * (f32x2){-sv01.x, sv01.y};
      c01[a] += sz2 * (f32x2){-v23.x, v23.y};
      c01[a] += sw2 * (f32x2){-sv23.x, -sv23.y};
      // o23 += sx*(vz,vw) + sy*(-vw,vz) + sz*(vx,-vy) + sw*(vy,vx)
      c23[a] += sx2 * v23;
      c23[a] += sy2 * (f32x2){-sv23.x, sv23.y};
      c23[a] += sz2 * (f32x2){v01.x, -v01.y};
      c23[a] += sw2 * sv01;
    }
  }

  // plain stores into this j-chunk's slab
  float* cp = CTXS + ((size_t)(js * NBH + bh) * L_SEQ + i) * HD + ag * 16;
  #pragma unroll
  for (int t = 0; t < 4; ++t) {
    float4 o = make_float4(c01[t].x, c01[t].y, c23[t].x, c23[t].y);
    ((float4*)cp)[t] = o;
  }
}

// ---------------------------------------------------------------------------
// Fused slab-reduce + output projection (replaces ctx_reduce + out gemm).
// Unlike R7: each block owns an EXCLUSIVE 32-row m-slice x 256-col n-half,
// so each ctx row's 12-slab sum happens once per n-half (A traffic 2x19MB
// over 48 blocks), feeding MFMA A-frags directly. No LDS, no fences
// (stream-ordered after berry). Block 128 = 2 waves (16-row strips);
// grid (2 n-halves, 24 m-slices). acc = 16 f32x4 = 64 VGPRs.
// A source: ctx[m=b*384+l][k=h*64+d] = sum_js CTXS[js][(b*8+h)*384+l][d].
// ---------------------------------------------------------------------------
__global__ __launch_bounds__(128, 2) void ctx_out_gemm(
    const float* __restrict__ CTXS, const __bf16* __restrict__ Wob,
    float* __restrict__ out)
{
  const int tid = threadIdx.x;
  const int wave = tid >> 6, lane = tid & 63;
  const int mr = lane & 15, quad = lane >> 4;
  const int m0 = blockIdx.y * 32 + wave * 16;
  const int n0 = blockIdx.x * 256;

  const int m = m0 + mr;                       // A row this lane loads
  const int batch = m / L_SEQ, l = m - batch * L_SEQ;

  f32x4 acc[16];
  #pragma unroll
  for (int nt = 0; nt < 16; ++nt) acc[nt] = (f32x4){0.f, 0.f, 0.f, 0.f};

  for (int k0 = 0; k0 < E_DIM; k0 += 32) {
    const int h = k0 >> 6;                     // head for this 32-col k-slice
    const int d = (k0 & 32) + quad * 8;        // offset within head dim
    const float* ap = CTXS + (((size_t)(batch * NHEAD + h) * L_SEQ) + l) * HD + d;
    float4 s0 = make_float4(0.f, 0.f, 0.f, 0.f);
    float4 s1 = make_float4(0.f, 0.f, 0.f, 0.f);
    #pragma unroll
    for (int js = 0; js < JSPLIT; ++js) {
      float4 v0 = *(const float4*)(ap + (size_t)js * PROJ_ELEMS);
      float4 v1 = *(const float4*)(ap + (size_t)js * PROJ_ELEMS + 4);
      s0.x += v0.x; s0.y += v0.y; s0.z += v0.z; s0.w += v0.w;
      s1.x += v1.x; s1.y += v1.y; s1.z += v1.z; s1.w += v1.w;
    }
    bf16x8 a = cvt8(s0, s1);
    const __bf16* bp = Wob + (size_t)(n0 + mr) * E_DIM + k0 + quad * 8;
    #pragma unroll 8
    for (int nt = 0; nt < 16; ++nt) {
      bf16x8 b = *(const bf16x8*)(bp + (size_t)nt * 16 * E_DIM);
      acc[nt] = __builtin_amdgcn_mfma_f32_16x16x32_bf16(a, b, acc[nt], 0, 0, 0);
    }
  }

  #pragma unroll
  for (int nt = 0; nt < 16; ++nt) {
    int n = n0 + nt * 16 + mr;
    #pragma unroll
    for (int r = 0; r < 4; ++r) {
      int mm = m0 + quad * 4 + r;
      out[(size_t)mm * E_DIM + n] = acc[nt][r];
    }
  }
}

// ---------------------------------------------------------------------------
// Workspace (R5 layout; CTXB slot now unused):
//   [0          .. 1572864)  Qw fp32
//   [1572864    .. 3145728)  Kw fp32
//   [3145728    .. 4718592)  Vw fp32
//   [4718592    .. 23592960) CTXS (12 slabs)   | xb|Wqb|Wkb|Wvb bf16 (pre-berry)
//   [23592960   .. 24117248) Wob bf16
// ---------------------------------------------------------------------------
extern "C" void kernel_launch(void* const* d_in, const int* in_sizes, int n_in,
                              void* d_out, int out_size, void* d_ws, size_t ws_size,
                              hipStream_t stream)
{
  const float* x     = (const float*)d_in[0];
  const float* Wq    = (const float*)d_in[1];
  const float* Wk    = (const float*)d_in[2];
  const float* Wv    = (const float*)d_in[3];
  const float* Wo    = (const float*)d_in[4];
  const float* dde_w = (const float*)d_in[5];
  const float* dde_b = (const float*)d_in[6];
  float* out = (float*)d_out;

  char* ws = (char*)d_ws;
  float* Qw   = (float*)(ws + 0);
  float* Kw   = (float*)(ws + 1572864);
  float* Vw   = (float*)(ws + 3145728);
  float* CTXS = (float*)(ws + 4718592);
  unsigned short* xb   = (unsigned short*)(ws + 4718592);   // dead before berry
  unsigned short* Wqb  = (unsigned short*)(ws + 5505024);
  unsigned short* Wkb  = (unsigned short*)(ws + 6029312);
  unsigned short* Wvb  = (unsigned short*)(ws + 6553600);
  unsigned short* Wob  = (unsigned short*)(ws + 23592960);

  // 1) fp32 -> bf16 conversions
  to_bf16_all<<<1408, 256, 0, stream>>>(x, Wq, Wk, Wv, Wo, xb, Wob);

  // 2) Q/K/V projections: pure-bf16 MFMA, head-scatter fp32 epilogue
  gemm_mfma<<<dim3(8, 12, 3), 256, 0, stream>>>(
      (const __bf16*)xb, (const __bf16*)Wqb, (const __bf16*)Wkb, (const __bf16*)Wvb,
      Qw, Kw, Vw, 2 * L_SEQ, E_DIM, E_DIM);

  // 3) fused pairwise core -> 12 fp32 slabs
  berry_main<<<dim3(JSPLIT, 12, NBH), 128, 0, stream>>>(
      Qw, Kw, Vw, dde_w, dde_b, CTXS);

  // 4) fused slab-reduce + output projection
  ctx_out_gemm<<<dim3(2, 24), 128, 0, stream>>>(CTXS, (const __bf16*)Wob, out);
}

// Round 13
// 165.642 us; speedup vs baseline: 1.3302x; 1.3302x over previous
//
#include <hip/hip_runtime.h>
#include <math.h>

#define L_SEQ 384
#define E_DIM 512
#define NHEAD 8
#define NBH   16
#define HD    64
#define JSPLIT 12
#define JTILE  32          // L_SEQ / JSPLIT
#define PROJ_ELEMS (NBH * L_SEQ * HD)   // 393216
#define LOG2E 1.44269504f

typedef __attribute__((ext_vector_type(8))) __bf16 bf16x8;
typedef __attribute__((ext_vector_type(4))) float f32x4;
typedef __attribute__((ext_vector_type(2))) float f32x2;

__device__ __forceinline__ float uniform_f(float v) {
  return __uint_as_float(__builtin_amdgcn_readfirstlane(__float_as_uint(v)));
}

__device__ __forceinline__ unsigned f2bf(float f) {   // RNE float->bf16 bits
  unsigned u = __float_as_uint(f);
  return (u + 0x7FFFu + ((u >> 16) & 1u)) >> 16;
}

// quad_perm DPP helpers (pure VALU, no LDS pipe)
__device__ __forceinline__ float quad_sum(float x) {
  x += __int_as_float(__builtin_amdgcn_mov_dpp(__float_as_int(x), 0xB1, 0xF, 0xF, 0)); // xor 1
  x += __int_as_float(__builtin_amdgcn_mov_dpp(__float_as_int(x), 0x4E, 0xF, 0xF, 0)); // xor 2
  return x;
}
template <int PAT>
__device__ __forceinline__ float quad_bcast(float x) {
  return __int_as_float(__builtin_amdgcn_mov_dpp(__float_as_int(x), PAT, 0xF, 0xF, 0));
}

// ---------------------------------------------------------------------------
// Convert x|Wq|Wk|Wv (contiguous dst1) and Wo (dst2) to bf16 (R5-proven).
// ---------------------------------------------------------------------------
__global__ __launch_bounds__(256) void to_bf16_all(
    const float* __restrict__ x, const float* __restrict__ Wq,
    const float* __restrict__ Wk, const float* __restrict__ Wv,
    const float* __restrict__ Wo, unsigned short* __restrict__ dst1,
    unsigned short* __restrict__ dst2)
{
  int e0 = (blockIdx.x * 256 + threadIdx.x) * 4;
  if (e0 >= 1441792) return;
  const float* src; unsigned short* d; int s;
  if (e0 < 393216)       { src = x;  s = e0;           d = dst1 + e0; }
  else if (e0 < 655360)  { src = Wq; s = e0 - 393216;  d = dst1 + e0; }
  else if (e0 < 917504)  { src = Wk; s = e0 - 655360;  d = dst1 + e0; }
  else if (e0 < 1179648) { src = Wv; s = e0 - 917504;  d = dst1 + e0; }
  else                   { src = Wo; s = e0 - 1179648; d = dst2 + s;  }
  float4 v = *(const float4*)(src + s);
  unsigned lo = f2bf(v.x) | (f2bf(v.y) << 16);
  unsigned hi = f2bf(v.z) | (f2bf(v.w) << 16);
  *(uint2*)d = make_uint2(lo, hi);
}

// ---------------------------------------------------------------------------
// Pure-bf16 MFMA GEMM (R5-proven). C = A @ B^T.
// Block 256 = 4 waves; tile 64x64; wave = 16-row strip, 4 n-tiles.
// mode 0: C[m*N+f]; mode 1: head-scatter C[((b*8+h)*L+l)*64+d].
// ---------------------------------------------------------------------------
__global__ __launch_bounds__(256) void gemm_mfma(
    const __bf16* __restrict__ A, const __bf16* __restrict__ B0,
    const __bf16* __restrict__ B1, const __bf16* __restrict__ B2,
    float* __restrict__ C0, float* __restrict__ C1, float* __restrict__ C2,
    int M, int N, int K, int mode)
{
  const int z = blockIdx.z;
  const __bf16* Bm = (z == 0) ? B0 : (z == 1) ? B1 : B2;
  float* Cp = (z == 0) ? C0 : (z == 1) ? C1 : C2;

  const int tid = threadIdx.x;
  const int wave = tid >> 6, lane = tid & 63;
  const int m0 = blockIdx.y * 64 + wave * 16;
  const int n0 = blockIdx.x * 64;
  const int mr = lane & 15, quad = lane >> 4;

  f32x4 acc[4];
  #pragma unroll
  for (int nt = 0; nt < 4; ++nt) acc[nt] = (f32x4){0.f, 0.f, 0.f, 0.f};

  const __bf16* ap = A + (size_t)(m0 + mr) * K + quad * 8;
  const __bf16* bp = Bm + (size_t)(n0 + mr) * K + quad * 8;

  #pragma unroll 4
  for (int k0 = 0; k0 < K; k0 += 32) {
    bf16x8 a = *(const bf16x8*)(ap + k0);
    #pragma unroll
    for (int nt = 0; nt < 4; ++nt) {
      bf16x8 b = *(const bf16x8*)(bp + (size_t)nt * 16 * K + k0);
      acc[nt] = __builtin_amdgcn_mfma_f32_16x16x32_bf16(a, b, acc[nt], 0, 0, 0);
    }
  }

  #pragma unroll
  for (int nt = 0; nt < 4; ++nt) {
    int n = n0 + nt * 16 + mr;
    #pragma unroll
    for (int r = 0; r < 4; ++r) {
      int m = m0 + quad * 4 + r;
      if (mode == 0) {
        Cp[(size_t)m * N + n] = acc[nt][r];
      } else {
        int b = m / L_SEQ, l = m % L_SEQ;
        int h = n >> 6, d = n & 63;
        Cp[((size_t)(b * NHEAD + h) * L_SEQ + l) * HD + d] = acc[nt][r];
      }
    }
  }
}

// ---------------------------------------------------------------------------
// Fused pairwise core v10 = R11 math (fp32 LDS — R12's bf16-LDS regressed),
// 256-thr blocks (64 i x 4 lanes) so one K/V tile serves 2x the i-rows
// (staging + K/V HBM re-reads halve), grid (12, 6, 16) = 1152 blocks.
// #pragma unroll 2 on jj: overlap the serial gate chain (quad_sum DPP ->
// fma -> exp2 -> rcp -> bcast) of jj with pk-FMA work of jj+1.
// ---------------------------------------------------------------------------
__global__ __launch_bounds__(256, 4) void berry_main(
    const float* __restrict__ Q, const float* __restrict__ K,
    const float* __restrict__ V, const float* __restrict__ dde_w,
    const float* __restrict__ dde_b, float* __restrict__ CTXS)
{
  __shared__ float kt[JTILE][HD];   // normalized k atoms
  __shared__ float vt[JTILE][HD];   // raw v

  const int tid = threadIdx.x;
  const int bh = blockIdx.z;
  const int i = blockIdx.y * 64 + (tid >> 2);
  const int ag = tid & 3;                 // lane-in-quad: atoms ag*4 .. ag*4+3
  const int js = blockIdx.x;
  const int j0 = js * JTILE;

  // this lane's gate row p = ag: weights * (-LOG2E/16), bias * (-LOG2E)
  float w0, w1, w2, w3, gbp;
  {
    float s[16];
    #pragma unroll
    for (int t = 0; t < 16; ++t) s[t] = uniform_f(dde_w[t]) * (-LOG2E * 0.0625f);
    float b0 = uniform_f(dde_b[0]) * -LOG2E, b1 = uniform_f(dde_b[1]) * -LOG2E;
    float b2 = uniform_f(dde_b[2]) * -LOG2E, b3 = uniform_f(dde_b[3]) * -LOG2E;
    w0  = (ag == 0) ? s[0]  : (ag == 1) ? s[4]  : (ag == 2) ? s[8]  : s[12];
    w1  = (ag == 0) ? s[1]  : (ag == 1) ? s[5]  : (ag == 2) ? s[9]  : s[13];
    w2  = (ag == 0) ? s[2]  : (ag == 1) ? s[6]  : (ag == 2) ? s[10] : s[14];
    w3  = (ag == 0) ? s[3]  : (ag == 1) ? s[7]  : (ag == 2) ? s[11] : s[15];
    gbp = (ag == 0) ? b0    : (ag == 1) ? b1    : (ag == 2) ? b2    : b3;
  }

  float4 qa[4];
  f32x2 c01[4], c23[4];
  const float* qp = Q + ((size_t)(bh * L_SEQ + i) * HD + ag * 16);
  #pragma unroll
  for (int t = 0; t < 4; ++t) {
    float4 q = ((const float4*)qp)[t];
    float d = q.x * q.x + q.y * q.y + q.z * q.z + q.w * q.w;
    float r = __builtin_amdgcn_rsqf(fmaxf(d, 1e-30f));
    qa[t].x = q.x * r; qa[t].y = q.y * r; qa[t].z = q.z * r; qa[t].w = q.w * r;
    c01[t] = (f32x2){0.f, 0.f};
    c23[t] = (f32x2){0.f, 0.f};
  }

  // stage K (normalized per atom: |ham(q,k)| = |q||k|) + V: 512 atoms, 2/thread
  #pragma unroll
  for (int p = 0; p < 2; ++p) {
    int idx = tid + p * 256;
    int jj = idx >> 4, at = idx & 15;
    size_t g = (size_t)(bh * L_SEQ + j0 + jj) * HD + at * 4;
    float4 kq = *(const float4*)(K + g);
    float d = kq.x * kq.x + kq.y * kq.y + kq.z * kq.z + kq.w * kq.w;
    float r = __builtin_amdgcn_rsqf(fmaxf(d, 1e-30f));
    kq.x *= r; kq.y *= r; kq.z *= r; kq.w *= r;
    *(float4*)&kt[jj][at * 4] = kq;
    *(float4*)&vt[jj][at * 4] = *(const float4*)(V + g);
  }
  __syncthreads();

  #pragma unroll 2
  for (int jj = 0; jj < JTILE; ++jj) {
    f32x2 h01[4], h23[4];
    f32x2 gs01 = (f32x2){0.f, 0.f}, gs23 = (f32x2){0.f, 0.f};

    #pragma unroll
    for (int a = 0; a < 4; ++a) {
      float4 kq = *(const float4*)&kt[jj][ag * 16 + a * 4];
      f32x2 k01 = (f32x2){kq.x, kq.y}, k23 = (f32x2){kq.z, kq.w};
      f32x2 s01 = (f32x2){kq.y, kq.x}, s23 = (f32x2){kq.w, kq.z};
      f32x2 qx2 = (f32x2){qa[a].x, qa[a].x};
      f32x2 qy2 = (f32x2){qa[a].y, qa[a].y};
      f32x2 qz2 = (f32x2){qa[a].z, qa[a].z};
      f32x2 qw2 = (f32x2){qa[a].w, qa[a].w};
      // h01 = qx*(kx,ky) + qy*(-ky,kx) + qz*(-kz,kw) + qw*(-kw,-kz)
      f32x2 t = qx2 * k01;
      t += qy2 * (f32x2){-s01.x, s01.y};
      t += qz2 * (f32x2){-k23.x, k23.y};
      t += qw2 * (f32x2){-s23.x, -s23.y};
      h01[a] = t;
      // h23 = qx*(kz,kw) + qy*(-kw,kz) + qz*(kx,-ky) + qw*(ky,kx)
      f32x2 u = qx2 * k23;
      u += qy2 * (f32x2){-s23.x, s23.y};
      u += qz2 * (f32x2){k01.x, -k01.y};
      u += qw2 * s01;
      h23[a] = u;
      gs01 += t; gs23 += u;
    }

    // 16-atom component sums across the quad (4 scalar DPP butterflies)
    float g0 = quad_sum(gs01.x), g1 = quad_sum(gs01.y);
    float g2 = quad_sum(gs23.x), g3 = quad_sum(gs23.y);

    // this lane's gate only (weights pre-scaled by -LOG2E/16), then share
    float tl = gbp + w0 * g0 + w1 * g1 + w2 * g2 + w3 * g3;
    float gown = __builtin_amdgcn_rcpf(1.f + __builtin_amdgcn_exp2f(tl));
    float gx = quad_bcast<0x00>(gown);
    float gy = quad_bcast<0x55>(gown);
    float gz = quad_bcast<0xAA>(gown);
    float gw_ = quad_bcast<0xFF>(gown);
    f32x2 gA = (f32x2){gx, gy}, gB = (f32x2){gz, gw_};

    #pragma unroll
    for (int a = 0; a < 4; ++a) {
      f32x2 sA = h01[a] * gA;            // (sx, sy)
      f32x2 sB = h23[a] * gB;            // (sz, sw)
      float4 vq = *(const float4*)&vt[jj][ag * 16 + a * 4];
      f32x2 v01 = (f32x2){vq.x, vq.y}, v23 = (f32x2){vq.z, vq.w};
      f32x2 sv01 = (f32x2){vq.y, vq.x}, sv23 = (f32x2){vq.w, vq.z};
      f32x2 sx2 = (f32x2){sA.x, sA.x}, sy2 = (f32x2){sA.y, sA.y};
      f32x2 sz2 = (f32x2){sB.x, sB.x}, sw2 = (f32x2){sB.y, sB.y};
      // o01 += sx*(vx,vy) + sy*(-vy,vx) + sz*(-vz,vw) + sw*(-vw,-vz)
      c01[a] += sx2 * v01;
      c01[a] += sy2 * (f32x2){-sv01.x, sv01.y};
      c01[a] += sz2 * (f32x2){-v23.x, v23.y};
      c01[a] += sw2 * (f32x2){-sv23.x, -sv23.y};
      // o23 += sx*(vz,vw) + sy*(-vw,vz) + sz*(vx,-vy) + sw*(vy,vx)
      c23[a] += sx2 * v23;
      c23[a] += sy2 * (f32x2){-sv23.x, sv23.y};
      c23[a] += sz2 * (f32x2){v01.x, -v01.y};
      c23[a] += sw2 * sv01;
    }
  }

  // plain stores into this j-chunk's slab
  float* cp = CTXS + ((size_t)(js * NBH + bh) * L_SEQ + i) * HD + ag * 16;
  #pragma unroll
  for (int t = 0; t < 4; ++t) {
    float4 o = make_float4(c01[t].x, c01[t].y, c23[t].x, c23[t].y);
    ((float4*)cp)[t] = o;
  }
}

// ---------------------------------------------------------------------------
// Sum the JSPLIT ctx slabs, transpose heads into (b,l,e), emit bf16 (R5).
// 384 blocks — wide and flat (R12 lesson: narrow fused reduce = HBM
// latency-chain disaster).
// ---------------------------------------------------------------------------
__global__ __launch_bounds__(256) void ctx_reduce(
    const float* __restrict__ CTXS, unsigned short* __restrict__ CTXB)
{
  int idx = blockIdx.x * 256 + threadIdx.x;      // over 98304 float4 groups
  int row = idx >> 4;                            // bh*L + i
  int d0 = (idx & 15) * 4;
  float4 s = make_float4(0.f, 0.f, 0.f, 0.f);
  #pragma unroll
  for (int js = 0; js < JSPLIT; ++js) {
    float4 v = *(const float4*)&CTXS[(size_t)js * PROJ_ELEMS + (size_t)row * HD + d0];
    s.x += v.x; s.y += v.y; s.z += v.z; s.w += v.w;
  }
  int bh = row / L_SEQ, i = row - bh * L_SEQ;
  int b = bh >> 3, h = bh & 7;
  unsigned lo = f2bf(s.x) | (f2bf(s.y) << 16);
  unsigned hi = f2bf(s.z) | (f2bf(s.w) << 16);
  *(uint2*)&CTXB[((size_t)(b * L_SEQ + i) * E_DIM) + h * HD + d0] = make_uint2(lo, hi);
}

// ---------------------------------------------------------------------------
// Workspace (R5-proven layout, 24,379,392 B):
//   [0          .. 1572864)  Qw fp32            | CTXB bf16 (after berry)
//   [1572864    .. 3145728)  Kw fp32
//   [3145728    .. 4718592)  Vw fp32
//   [4718592    .. 23592960) CTXS (12 slabs)    | xb|Wqb|Wkb|Wvb bf16 (pre-berry)
//   [23592960   .. 24117248) Wob bf16
// ---------------------------------------------------------------------------
extern "C" void kernel_launch(void* const* d_in, const int* in_sizes, int n_in,
                              void* d_out, int out_size, void* d_ws, size_t ws_size,
                              hipStream_t stream)
{
  const float* x     = (const float*)d_in[0];
  const float* Wq    = (const float*)d_in[1];
  const float* Wk    = (const float*)d_in[2];
  const float* Wv    = (const float*)d_in[3];
  const float* Wo    = (const float*)d_in[4];
  const float* dde_w = (const float*)d_in[5];
  const float* dde_b = (const float*)d_in[6];
  float* out = (float*)d_out;

  char* ws = (char*)d_ws;
  float* Qw   = (float*)(ws + 0);
  float* Kw   = (float*)(ws + 1572864);
  float* Vw   = (float*)(ws + 3145728);
  float* CTXS = (float*)(ws + 4718592);
  unsigned short* xb   = (unsigned short*)(ws + 4718592);   // dead before berry
  unsigned short* Wqb  = (unsigned short*)(ws + 5505024);
  unsigned short* Wkb  = (unsigned short*)(ws + 6029312);
  unsigned short* Wvb  = (unsigned short*)(ws + 6553600);
  unsigned short* Wob  = (unsigned short*)(ws + 23592960);
  unsigned short* CTXB = (unsigned short*)(ws + 0);         // born after Qw dead

  // 1) fp32 -> bf16 conversions
  to_bf16_all<<<1408, 256, 0, stream>>>(x, Wq, Wk, Wv, Wo, xb, Wob);

  // 2) Q/K/V projections: pure-bf16 MFMA, head-scatter fp32 epilogue
  gemm_mfma<<<dim3(8, 12, 3), 256, 0, stream>>>(
      (const __bf16*)xb, (const __bf16*)Wqb, (const __bf16*)Wkb, (const __bf16*)Wvb,
      Qw, Kw, Vw, 2 * L_SEQ, E_DIM, E_DIM, 1);

  // 3) fused pairwise core -> 12 fp32 slabs
  berry_main<<<dim3(JSPLIT, 6, NBH), 256, 0, stream>>>(
      Qw, Kw, Vw, dde_w, dde_b, CTXS);

  // 4) slab reduction + head transpose -> bf16
  ctx_reduce<<<384, 256, 0, stream>>>(CTXS, CTXB);

  // 5) output projection: pure-bf16 MFMA, fp32 out
  gemm_mfma<<<dim3(8, 12, 1), 256, 0, stream>>>(
      (const __bf16*)CTXB, (const __bf16*)Wob, nullptr, nullptr,
      out, nullptr, nullptr, 2 * L_SEQ, E_DIM, E_DIM, 0);
}